// Round 1
// baseline (937.793 us; speedup 1.0000x reference)
//
#include <hip/hip_runtime.h>
#include <math.h>

// Problem constants
#define Bn    32
#define Tn    2000
#define ENC2n 1024
#define ATTNn 512
#define DECn  512
#define NKn   10
#define KWn   100
#define PADn  50

// workspace layout (in floats)
// tmpconv [B*T][NK] at 0 ; dec_e [B][ATTN] at OFF_DEC ; score [B*T] at OFF_SCORE
#define OFF_DEC   (Bn * Tn * NKn)
#define OFF_SCORE (OFF_DEC + Bn * ATTNn)

__device__ __forceinline__ void fma4(float4& c, float a, const float4& b) {
  c.x = fmaf(a, b.x, c.x);
  c.y = fmaf(a, b.y, c.y);
  c.z = fmaf(a, b.z, c.z);
  c.w = fmaf(a, b.w, c.w);
}

__device__ __forceinline__ float f4get(const float4& v, int i) {
  switch (i & 3) {
    case 0: return v.x;
    case 1: return v.y;
    case 2: return v.z;
    default: return v.w;
  }
}

// ---------------------------------------------------------------------------
// Kernel 1: location conv  tmpconv[b,t,k] = sum_i alpha[b, t+i-50] * Wconv[k,i]
// Also zeroes the score accumulator (must precede k_main on the stream).
// ---------------------------------------------------------------------------
__global__ __launch_bounds__(256) void k_conv(const float* __restrict__ alpha,
                                              const float* __restrict__ Wconv,
                                              float* __restrict__ ws) {
  __shared__ float sh[256 + KWn - 1];   // alpha window [t0-50, t0+255+49]
  __shared__ float wc[NKn * KWn];
  const int b = blockIdx.y;
  const int t0 = blockIdx.x * 256;
  const int tid = threadIdx.x;

  for (int i = tid; i < NKn * KWn; i += 256) wc[i] = Wconv[i];
  const float* __restrict__ arow = alpha + b * Tn;
  for (int i = tid; i < 256 + KWn - 1; i += 256) {
    const int t = t0 - PADn + i;
    sh[i] = (t >= 0 && t < Tn) ? arow[t] : 0.f;
  }
  __syncthreads();

  const int t = t0 + tid;
  if (t < Tn) {
    float acc[NKn];
#pragma unroll
    for (int k = 0; k < NKn; ++k) acc[k] = 0.f;
    for (int i = 0; i < KWn; ++i) {
      const float a = sh[tid + i];
#pragma unroll
      for (int k = 0; k < NKn; ++k) acc[k] = fmaf(a, wc[k * KWn + i], acc[k]);
    }
    float* tp = ws + (size_t)(b * Tn + t) * NKn;
#pragma unroll
    for (int k = 0; k < NKn; ++k) tp[k] = acc[k];
    ws[OFF_SCORE + b * Tn + t] = 0.f;   // zero score accumulator
  }
}

// ---------------------------------------------------------------------------
// Kernel 2: dec_e[b,a] = sum_d hidden[b,d] * Wdec[d,a]
// ---------------------------------------------------------------------------
__global__ __launch_bounds__(512) void k_dec(const float* __restrict__ h,
                                             const float* __restrict__ Wdec,
                                             float* __restrict__ ws) {
  __shared__ float sh[DECn];
  const int b = blockIdx.x;
  const int a = threadIdx.x;
  sh[a] = h[b * DECn + a];
  __syncthreads();
  float acc = 0.f;
  for (int d = 0; d < DECn; ++d) acc = fmaf(sh[d], Wdec[d * ATTNn + a], acc);
  ws[OFF_DEC + b * ATTNn + a] = acc;
}

// ---------------------------------------------------------------------------
// Kernel 3: fused GEMM (enc @ W_enc) + bias + conv-feature expansion + tanh
//           + w_score dot  -> partial score, atomically combined.
// Tile: TM=64 rows x TN=256 cols, BK=32.  256 threads, reg tile 4x16.
// ---------------------------------------------------------------------------
#define TM 64
#define TN 256
#define BK 32

__global__ __launch_bounds__(256) void k_main(
    const float* __restrict__ A,      // [64000][1024]
    const float* __restrict__ Wenc,   // [1024][512]
    const float* __restrict__ benc,   // [512]
    const float* __restrict__ Wc2s,   // [10][512]
    const float* __restrict__ wscore, // [512]
    float* __restrict__ ws) {
  __shared__ float As[BK][TM];    // 8 KB
  __shared__ float Wsh[BK][TN];   // 32 KB
  const int tid = threadIdx.x;
  const int row0 = blockIdx.x * TM;
  const int c0 = blockIdx.y * TN;
  const int g = tid >> 4, x = tid & 15;
  const int m0 = g * 4, x4 = x * 4;

  float4 acc[4][4];
#pragma unroll
  for (int r = 0; r < 4; ++r)
#pragma unroll
    for (int j = 0; j < 4; ++j) acc[r][j] = make_float4(0.f, 0.f, 0.f, 0.f);

  // A staging map: thread -> (row = tid>>2, 8 consecutive k at (tid&3)*8)
  const int ar = tid >> 2, akk = (tid & 3) * 8;
  const float* __restrict__ asrc = A + (size_t)(row0 + ar) * ENC2n + akk;
  // W staging map: per j, k-row = j*4 + (tid>>6), float4-col = tid&63 (coalesced)
  const int w4 = tid >> 6, c4 = (tid & 63) * 4;
  const float* __restrict__ wsrc = Wenc + (size_t)w4 * ATTNn + c0 + c4;

  for (int k0 = 0; k0 < ENC2n; k0 += BK) {
    const float4 a0 = *(const float4*)(asrc + k0);
    const float4 a1 = *(const float4*)(asrc + k0 + 4);
    As[akk + 0][ar] = a0.x; As[akk + 1][ar] = a0.y;
    As[akk + 2][ar] = a0.z; As[akk + 3][ar] = a0.w;
    As[akk + 4][ar] = a1.x; As[akk + 5][ar] = a1.y;
    As[akk + 6][ar] = a1.z; As[akk + 7][ar] = a1.w;
#pragma unroll
    for (int j = 0; j < 8; ++j) {
      const float4 v = *(const float4*)(wsrc + (size_t)(k0 + j * 4) * ATTNn);
      *(float4*)&Wsh[j * 4 + w4][c4] = v;
    }
    __syncthreads();
#pragma unroll 4
    for (int k = 0; k < BK; ++k) {
      const float4 av = *(const float4*)&As[k][m0];
      const float4 w0 = *(const float4*)&Wsh[k][x4];
      const float4 w1 = *(const float4*)&Wsh[k][64 + x4];
      const float4 w2 = *(const float4*)&Wsh[k][128 + x4];
      const float4 w3 = *(const float4*)&Wsh[k][192 + x4];
      fma4(acc[0][0], av.x, w0); fma4(acc[0][1], av.x, w1);
      fma4(acc[0][2], av.x, w2); fma4(acc[0][3], av.x, w3);
      fma4(acc[1][0], av.y, w0); fma4(acc[1][1], av.y, w1);
      fma4(acc[1][2], av.y, w2); fma4(acc[1][3], av.y, w3);
      fma4(acc[2][0], av.z, w0); fma4(acc[2][1], av.z, w1);
      fma4(acc[2][2], av.z, w2); fma4(acc[2][3], av.z, w3);
      fma4(acc[3][0], av.w, w0); fma4(acc[3][1], av.w, w1);
      fma4(acc[3][2], av.w, w2); fma4(acc[3][3], av.w, w3);
    }
    __syncthreads();
  }

  // Epilogue: v = gemm + b_enc[c] + dec_e[b,c] + sum_k tmp[row,k]*Wc2s[k,c]
  //           part[row] += wscore[c] * tanh(v)
  float tkv[4][NKn];
  int brow[4];
#pragma unroll
  for (int r = 0; r < 4; ++r) {
    const int row = row0 + m0 + r;
    brow[r] = row / Tn;
    const float* tp = ws + (size_t)row * NKn;
#pragma unroll
    for (int k = 0; k < NKn; ++k) tkv[r][k] = tp[k];
  }
  float part[4] = {0.f, 0.f, 0.f, 0.f};
  const float* __restrict__ dec0 = ws + OFF_DEC;
#pragma unroll
  for (int j = 0; j < 4; ++j) {
#pragma unroll
    for (int jj = 0; jj < 4; ++jj) {
      const int c = c0 + j * 64 + x4 + jj;
      const float bb = benc[c];
      const float wsc = wscore[c];
      float wc2[NKn];
#pragma unroll
      for (int k = 0; k < NKn; ++k) wc2[k] = Wc2s[k * ATTNn + c];
#pragma unroll
      for (int r = 0; r < 4; ++r) {
        float v = f4get(acc[r][j], jj) + bb + dec0[brow[r] * ATTNn + c];
#pragma unroll
        for (int k = 0; k < NKn; ++k) v = fmaf(tkv[r][k], wc2[k], v);
        part[r] += wsc * tanhf(v);
      }
    }
  }
#pragma unroll
  for (int r = 0; r < 4; ++r) {
    float p = part[r];
    p += __shfl_down(p, 8, 16);
    p += __shfl_down(p, 4, 16);
    p += __shfl_down(p, 2, 16);
    p += __shfl_down(p, 1, 16);
    if (x == 0) atomicAdd(&ws[OFF_SCORE + row0 + m0 + r], p);
  }
}

// ---------------------------------------------------------------------------
// Kernel 4: masked softmax over T per batch row -> alpha
// ---------------------------------------------------------------------------
__global__ __launch_bounds__(256) void k_softmax(const float* __restrict__ ws,
                                                 const float* __restrict__ mask,
                                                 float* __restrict__ out) {
  const int b = blockIdx.x, tid = threadIdx.x;
  const float* __restrict__ s = ws + OFF_SCORE + b * Tn;
  const float* __restrict__ mrow = mask + b * Tn;
  float* __restrict__ orow = out + b * Tn;
  __shared__ float red[4];

  float m = -1e30f;
  for (int t = tid; t < Tn; t += 256) m = fmaxf(m, s[t]);
#pragma unroll
  for (int off = 32; off; off >>= 1) m = fmaxf(m, __shfl_down(m, off));
  if ((tid & 63) == 0) red[tid >> 6] = m;
  __syncthreads();
  m = fmaxf(fmaxf(red[0], red[1]), fmaxf(red[2], red[3]));
  __syncthreads();

  float sum = 0.f;
  for (int t = tid; t < Tn; t += 256) {
    const float e = expf(s[t] - m) * mrow[t];
    orow[t] = e;
    sum += e;
  }
#pragma unroll
  for (int off = 32; off; off >>= 1) sum += __shfl_down(sum, off);
  if ((tid & 63) == 0) red[tid >> 6] = sum;
  __syncthreads();
  sum = red[0] + red[1] + red[2] + red[3];
  const float inv = 1.f / sum;
  for (int t = tid; t < Tn; t += 256) orow[t] *= inv;
}

// ---------------------------------------------------------------------------
extern "C" void kernel_launch(void* const* d_in, const int* in_sizes, int n_in,
                              void* d_out, int out_size, void* d_ws, size_t ws_size,
                              hipStream_t stream) {
  const float* enc   = (const float*)d_in[0];
  const float* hid   = (const float*)d_in[1];
  const float* alpha = (const float*)d_in[2];
  const float* mask  = (const float*)d_in[3];
  const float* Wconv = (const float*)d_in[4];
  const float* Wc2s  = (const float*)d_in[5];
  const float* Wenc  = (const float*)d_in[6];
  const float* benc  = (const float*)d_in[7];
  const float* Wdec  = (const float*)d_in[8];
  const float* wscr  = (const float*)d_in[9];
  float* out = (float*)d_out;
  float* ws  = (float*)d_ws;

  k_conv<<<dim3((Tn + 255) / 256, Bn), 256, 0, stream>>>(alpha, Wconv, ws);
  k_dec<<<Bn, DECn, 0, stream>>>(hid, Wdec, ws);
  k_main<<<dim3((Bn * Tn) / TM, ATTNn / TN), 256, 0, stream>>>(enc, Wenc, benc,
                                                               Wc2s, wscr, ws);
  k_softmax<<<Bn, 256, 0, stream>>>(ws, mask, out);
}

// Round 2
// 298.046 us; speedup vs baseline: 3.1465x; 3.1465x over previous
//
#include <hip/hip_runtime.h>
#include <math.h>

// Problem constants
#define Bn    32
#define Tn    2000
#define Mrows (Bn * Tn)        // 64000
#define ENC2n 1024
#define ATTNn 512
#define DECn  512
#define NKn   10
#define KWn   100
#define PADn  50

// workspace layout (floats):
//   [0, 640000)            tmpconv [64000][10]
//   [OFF_DB, +16384)       DB[32][512] = b_enc + dec_e
//   [OFF_SCORE, +64000)    score [64000]
//   [OFF_WT, +262144)      Wt as f16 [512][1024]  (transposed W_enc)
#define OFF_DB    (Mrows * NKn)
#define OFF_SCORE (OFF_DB + Bn * ATTNn)
#define OFF_WT    (OFF_SCORE + Mrows)

typedef _Float16 v8h __attribute__((ext_vector_type(8)));
typedef float f32x4 __attribute__((ext_vector_type(4)));

__device__ __forceinline__ float fast_tanh(float v) {
  const float e = __expf(2.f * v);
  return 1.f - 2.f * __builtin_amdgcn_rcpf(e + 1.f);
}

// ---------------------------------------------------------------------------
// k_wt: W_enc [1024][512] f32 -> Wt [512][1024] f16 (transpose + convert)
// ---------------------------------------------------------------------------
__global__ __launch_bounds__(256) void k_wt(const float* __restrict__ W,
                                            _Float16* __restrict__ Wt) {
  __shared__ float sh[32][33];
  const int x = threadIdx.x & 31, y = threadIdx.x >> 5;  // y: 0..7
  const int k0 = blockIdx.x * 32, c0 = blockIdx.y * 32;
  for (int i = y; i < 32; i += 8) sh[i][x] = W[(size_t)(k0 + i) * ATTNn + c0 + x];
  __syncthreads();
  for (int i = y; i < 32; i += 8)
    Wt[(size_t)(c0 + i) * ENC2n + k0 + x] = (_Float16)sh[x][i];
}

// ---------------------------------------------------------------------------
// k_conv: tmpconv[b,t,k] = sum_i alpha[b,t+i-50]*Wconv[k,i]; zero score acc
// ---------------------------------------------------------------------------
__global__ __launch_bounds__(256) void k_conv(const float* __restrict__ alpha,
                                              const float* __restrict__ Wconv,
                                              float* __restrict__ ws) {
  __shared__ float sh[256 + KWn - 1];
  __shared__ float wc[NKn * KWn];
  const int b = blockIdx.y;
  const int t0 = blockIdx.x * 256;
  const int tid = threadIdx.x;

  for (int i = tid; i < NKn * KWn; i += 256) wc[i] = Wconv[i];
  const float* __restrict__ arow = alpha + b * Tn;
  for (int i = tid; i < 256 + KWn - 1; i += 256) {
    const int t = t0 - PADn + i;
    sh[i] = (t >= 0 && t < Tn) ? arow[t] : 0.f;
  }
  __syncthreads();

  const int t = t0 + tid;
  if (t < Tn) {
    float acc[NKn];
#pragma unroll
    for (int k = 0; k < NKn; ++k) acc[k] = 0.f;
    for (int i = 0; i < KWn; ++i) {
      const float a = sh[tid + i];
#pragma unroll
      for (int k = 0; k < NKn; ++k) acc[k] = fmaf(a, wc[k * KWn + i], acc[k]);
    }
    float* tp = ws + (size_t)(b * Tn + t) * NKn;
#pragma unroll
    for (int k = 0; k < NKn; ++k) tp[k] = acc[k];
    ws[OFF_SCORE + b * Tn + t] = 0.f;
  }
}

// ---------------------------------------------------------------------------
// k_dec: DB[b,a] = b_enc[a] + sum_d h[b,d]*Wdec[d,a]
// ---------------------------------------------------------------------------
__global__ __launch_bounds__(512) void k_dec(const float* __restrict__ h,
                                             const float* __restrict__ Wdec,
                                             const float* __restrict__ benc,
                                             float* __restrict__ ws) {
  __shared__ float sh[DECn];
  const int b = blockIdx.x;
  const int a = threadIdx.x;
  sh[a] = h[b * DECn + a];
  __syncthreads();
  float acc = 0.f;
  for (int d = 0; d < DECn; ++d) acc = fmaf(sh[d], Wdec[d * ATTNn + a], acc);
  ws[OFF_DB + b * ATTNn + a] = benc[a] + acc;
}

// ---------------------------------------------------------------------------
// k_main: fused f16-MFMA GEMM (enc @ W_enc) + DB + conv-expansion + tanh
//         + w_score dot -> score (atomic across the 4 column blocks)
// 128x128 tile, KT=64, 4 waves, each wave 64x64 (4x4 frags of 16x16x32)
// ---------------------------------------------------------------------------
#define BM 128
#define BN 128
#define KT 64
#define LDK 72   // +8 f16 pad: row stride 144 B -> 2-way bank alias (free)

__global__ __launch_bounds__(256) void k_main(
    const float* __restrict__ A,        // [64000][1024] f32
    const _Float16* __restrict__ Wt,    // [512][1024] f16
    const float* __restrict__ Wc2s,     // [10][512]
    const float* __restrict__ wscore,   // [512]
    float* __restrict__ ws) {
  __shared__ _Float16 Asl[BM][LDK];   // 18 KB
  __shared__ _Float16 Wsl[BN][LDK];   // 18 KB
  const int tid = threadIdx.x;
  const int lane = tid & 63;
  const int wv = tid >> 6;
  const int wm = wv >> 1, wn = wv & 1;           // wave tile: rows wm*64, cols wn*64
  const int row0 = blockIdx.x * BM;
  const int c0 = blockIdx.y * BN;

  // staging maps: thread -> (row/col = tid>>1, k-half = (tid&1)*32)
  const int sr = tid >> 1, sh32 = (tid & 1) * 32;
  const float* __restrict__ asrc = A + (size_t)(row0 + sr) * ENC2n + sh32;
  const _Float16* __restrict__ wsrc = Wt + (size_t)(c0 + sr) * ENC2n + sh32;

  f32x4 acc[4][4];
#pragma unroll
  for (int m = 0; m < 4; ++m)
#pragma unroll
    for (int n = 0; n < 4; ++n) acc[m][n] = (f32x4)0.f;

  const int lr = lane & 15, lg = lane >> 4;

  for (int k0 = 0; k0 < ENC2n; k0 += KT) {
    // issue global loads (overlap tail of previous compute)
    float4 av0 = *(const float4*)(asrc + k0);
    float4 av1 = *(const float4*)(asrc + k0 + 4);
    float4 av2 = *(const float4*)(asrc + k0 + 8);
    float4 av3 = *(const float4*)(asrc + k0 + 12);
    float4 av4 = *(const float4*)(asrc + k0 + 16);
    float4 av5 = *(const float4*)(asrc + k0 + 20);
    float4 av6 = *(const float4*)(asrc + k0 + 24);
    float4 av7 = *(const float4*)(asrc + k0 + 28);
    v8h wv0 = *(const v8h*)(wsrc + k0);
    v8h wv1 = *(const v8h*)(wsrc + k0 + 8);
    v8h wv2 = *(const v8h*)(wsrc + k0 + 16);
    v8h wv3 = *(const v8h*)(wsrc + k0 + 24);

    __syncthreads();   // previous compute done reading LDS

    v8h h0, h1, h2, h3;
    h0[0]=(_Float16)av0.x; h0[1]=(_Float16)av0.y; h0[2]=(_Float16)av0.z; h0[3]=(_Float16)av0.w;
    h0[4]=(_Float16)av1.x; h0[5]=(_Float16)av1.y; h0[6]=(_Float16)av1.z; h0[7]=(_Float16)av1.w;
    h1[0]=(_Float16)av2.x; h1[1]=(_Float16)av2.y; h1[2]=(_Float16)av2.z; h1[3]=(_Float16)av2.w;
    h1[4]=(_Float16)av3.x; h1[5]=(_Float16)av3.y; h1[6]=(_Float16)av3.z; h1[7]=(_Float16)av3.w;
    h2[0]=(_Float16)av4.x; h2[1]=(_Float16)av4.y; h2[2]=(_Float16)av4.z; h2[3]=(_Float16)av4.w;
    h2[4]=(_Float16)av5.x; h2[5]=(_Float16)av5.y; h2[6]=(_Float16)av5.z; h2[7]=(_Float16)av5.w;
    h3[0]=(_Float16)av6.x; h3[1]=(_Float16)av6.y; h3[2]=(_Float16)av6.z; h3[3]=(_Float16)av6.w;
    h3[4]=(_Float16)av7.x; h3[5]=(_Float16)av7.y; h3[6]=(_Float16)av7.z; h3[7]=(_Float16)av7.w;
    *(v8h*)&Asl[sr][sh32 + 0]  = h0;
    *(v8h*)&Asl[sr][sh32 + 8]  = h1;
    *(v8h*)&Asl[sr][sh32 + 16] = h2;
    *(v8h*)&Asl[sr][sh32 + 24] = h3;
    *(v8h*)&Wsl[sr][sh32 + 0]  = wv0;
    *(v8h*)&Wsl[sr][sh32 + 8]  = wv1;
    *(v8h*)&Wsl[sr][sh32 + 16] = wv2;
    *(v8h*)&Wsl[sr][sh32 + 24] = wv3;

    __syncthreads();

#pragma unroll
    for (int ks = 0; ks < 2; ++ks) {
      const int kk = ks * 32 + lg * 8;
      v8h af[4], bf[4];
#pragma unroll
      for (int m = 0; m < 4; ++m) af[m] = *(const v8h*)&Asl[wm * 64 + m * 16 + lr][kk];
#pragma unroll
      for (int n = 0; n < 4; ++n) bf[n] = *(const v8h*)&Wsl[wn * 64 + n * 16 + lr][kk];
#pragma unroll
      for (int m = 0; m < 4; ++m)
#pragma unroll
        for (int n = 0; n < 4; ++n)
          acc[m][n] = __builtin_amdgcn_mfma_f32_16x16x32_f16(af[m], bf[n], acc[m][n], 0, 0, 0);
    }
  }

  // ---- epilogue ----
  __syncthreads();
  float* tcs = (float*)&Asl[0][0];          // reuse LDS: tmpconv slice [128][10]
  {
    const float* __restrict__ tsrc = ws + (size_t)row0 * NKn;
    for (int i = tid; i < BM * NKn; i += 256) tcs[i] = tsrc[i];
  }
  __syncthreads();

  const float* __restrict__ DB = ws + OFF_DB;
  float wc2[4][NKn], wsc[4];
  int cl[4];
#pragma unroll
  for (int fn = 0; fn < 4; ++fn) {
    cl[fn] = c0 + wn * 64 + fn * 16 + lr;
    wsc[fn] = wscore[cl[fn]];
#pragma unroll
    for (int k = 0; k < NKn; ++k) wc2[fn][k] = Wc2s[k * ATTNn + cl[fn]];
  }

#pragma unroll
  for (int fm = 0; fm < 4; ++fm) {
#pragma unroll
    for (int r = 0; r < 4; ++r) {
      const int rowL = wm * 64 + fm * 16 + lg * 4 + r;
      const int grow = row0 + rowL;
      const int b = grow / Tn;
      const float* __restrict__ tk = &tcs[rowL * NKn];
      float tkv[NKn];
#pragma unroll
      for (int k = 0; k < NKn; ++k) tkv[k] = tk[k];
      float p = 0.f;
#pragma unroll
      for (int fn = 0; fn < 4; ++fn) {
        float v = acc[fm][fn][r] + DB[b * ATTNn + cl[fn]];
#pragma unroll
        for (int k = 0; k < NKn; ++k) v = fmaf(tkv[k], wc2[fn][k], v);
        p = fmaf(wsc[fn], fast_tanh(v), p);
      }
      p += __shfl_down(p, 8, 16);
      p += __shfl_down(p, 4, 16);
      p += __shfl_down(p, 2, 16);
      p += __shfl_down(p, 1, 16);
      if (lr == 0) atomicAdd(&ws[OFF_SCORE + grow], p);
    }
  }
}

// ---------------------------------------------------------------------------
// k_softmax: masked softmax over T per batch row
// ---------------------------------------------------------------------------
__global__ __launch_bounds__(256) void k_softmax(const float* __restrict__ ws,
                                                 const float* __restrict__ mask,
                                                 float* __restrict__ out) {
  const int b = blockIdx.x, tid = threadIdx.x;
  const float* __restrict__ s = ws + OFF_SCORE + b * Tn;
  const float* __restrict__ mrow = mask + b * Tn;
  float* __restrict__ orow = out + b * Tn;
  __shared__ float red[4];

  float m = -1e30f;
  for (int t = tid; t < Tn; t += 256) m = fmaxf(m, s[t]);
#pragma unroll
  for (int off = 32; off; off >>= 1) m = fmaxf(m, __shfl_down(m, off));
  if ((tid & 63) == 0) red[tid >> 6] = m;
  __syncthreads();
  m = fmaxf(fmaxf(red[0], red[1]), fmaxf(red[2], red[3]));
  __syncthreads();

  float sum = 0.f;
  for (int t = tid; t < Tn; t += 256) {
    const float e = expf(s[t] - m) * mrow[t];
    orow[t] = e;
    sum += e;
  }
#pragma unroll
  for (int off = 32; off; off >>= 1) sum += __shfl_down(sum, off);
  if ((tid & 63) == 0) red[tid >> 6] = sum;
  __syncthreads();
  sum = red[0] + red[1] + red[2] + red[3];
  const float inv = 1.f / sum;
  for (int t = tid; t < Tn; t += 256) orow[t] *= inv;
}

// ---------------------------------------------------------------------------
extern "C" void kernel_launch(void* const* d_in, const int* in_sizes, int n_in,
                              void* d_out, int out_size, void* d_ws, size_t ws_size,
                              hipStream_t stream) {
  const float* enc   = (const float*)d_in[0];
  const float* hid   = (const float*)d_in[1];
  const float* alpha = (const float*)d_in[2];
  const float* mask  = (const float*)d_in[3];
  const float* Wconv = (const float*)d_in[4];
  const float* Wc2s  = (const float*)d_in[5];
  const float* Wenc  = (const float*)d_in[6];
  const float* benc  = (const float*)d_in[7];
  const float* Wdec  = (const float*)d_in[8];
  const float* wscr  = (const float*)d_in[9];
  float* out = (float*)d_out;
  float* ws  = (float*)d_ws;
  _Float16* Wt = (_Float16*)(ws + OFF_WT);

  k_wt<<<dim3(ENC2n / 32, ATTNn / 32), 256, 0, stream>>>(Wenc, Wt);
  k_conv<<<dim3((Tn + 255) / 256, Bn), 256, 0, stream>>>(alpha, Wconv, ws);
  k_dec<<<Bn, DECn, 0, stream>>>(hid, Wdec, benc, ws);
  k_main<<<dim3(Mrows / BM, ATTNn / BN), 256, 0, stream>>>(enc, Wt, Wc2s, wscr, ws);
  k_softmax<<<Bn, 256, 0, stream>>>(ws, mask, out);
}

// Round 3
// 259.298 us; speedup vs baseline: 3.6167x; 1.1494x over previous
//
#include <hip/hip_runtime.h>
#include <math.h>

// Problem constants
#define Bn    32
#define Tn    2000
#define Mrows (Bn * Tn)        // 64000
#define ENC2n 1024
#define ATTNn 512
#define DECn  512
#define NKn   10
#define KWn   100
#define PADn  50

// workspace layout (floats):
//   [0, 640000)            tmpconv [64000][10]
//   [OFF_DB, +16384)       DB[32][512] = b_enc + dec_e
//   [OFF_SCORE, +64000)    score [64000]
//   [OFF_WT, +262144)      Wt as f16 [512][1024]  (transposed W_enc)
#define OFF_DB    (Mrows * NKn)
#define OFF_SCORE (OFF_DB + Bn * ATTNn)
#define OFF_WT    (OFF_SCORE + Mrows)

typedef _Float16 v8h __attribute__((ext_vector_type(8)));
typedef float f32x4 __attribute__((ext_vector_type(4)));

__device__ __forceinline__ float fast_tanh(float v) {
  const float e = __expf(2.f * v);
  return 1.f - 2.f * __builtin_amdgcn_rcpf(e + 1.f);
}

// ---------------------------------------------------------------------------
// k_wt: W_enc [1024][512] f32 -> Wt [512][1024] f16 (transpose + convert)
// ---------------------------------------------------------------------------
__global__ __launch_bounds__(256) void k_wt(const float* __restrict__ W,
                                            _Float16* __restrict__ Wt) {
  __shared__ float sh[32][33];
  const int x = threadIdx.x & 31, y = threadIdx.x >> 5;  // y: 0..7
  const int k0 = blockIdx.x * 32, c0 = blockIdx.y * 32;
  for (int i = y; i < 32; i += 8) sh[i][x] = W[(size_t)(k0 + i) * ATTNn + c0 + x];
  __syncthreads();
  for (int i = y; i < 32; i += 8)
    Wt[(size_t)(c0 + i) * ENC2n + k0 + x] = (_Float16)sh[x][i];
}

// ---------------------------------------------------------------------------
// k_conv: tmpconv[b,t,k] = sum_i alpha[b,t+i-50]*Wconv[k,i]; zero score acc
// ---------------------------------------------------------------------------
__global__ __launch_bounds__(256) void k_conv(const float* __restrict__ alpha,
                                              const float* __restrict__ Wconv,
                                              float* __restrict__ ws) {
  __shared__ float sh[256 + KWn - 1];
  __shared__ float wc[NKn * KWn];
  const int b = blockIdx.y;
  const int t0 = blockIdx.x * 256;
  const int tid = threadIdx.x;

  for (int i = tid; i < NKn * KWn; i += 256) wc[i] = Wconv[i];
  const float* __restrict__ arow = alpha + b * Tn;
  for (int i = tid; i < 256 + KWn - 1; i += 256) {
    const int t = t0 - PADn + i;
    sh[i] = (t >= 0 && t < Tn) ? arow[t] : 0.f;
  }
  __syncthreads();

  const int t = t0 + tid;
  if (t < Tn) {
    float acc[NKn];
#pragma unroll
    for (int k = 0; k < NKn; ++k) acc[k] = 0.f;
    for (int i = 0; i < KWn; ++i) {
      const float a = sh[tid + i];
#pragma unroll
      for (int k = 0; k < NKn; ++k) acc[k] = fmaf(a, wc[k * KWn + i], acc[k]);
    }
    float* tp = ws + (size_t)(b * Tn + t) * NKn;
#pragma unroll
    for (int k = 0; k < NKn; ++k) tp[k] = acc[k];
    ws[OFF_SCORE + b * Tn + t] = 0.f;
  }
}

// ---------------------------------------------------------------------------
// k_dec: DB[b,a] = b_enc[a] + sum_d h[b,d]*Wdec[d,a]
// ---------------------------------------------------------------------------
__global__ __launch_bounds__(512) void k_dec(const float* __restrict__ h,
                                             const float* __restrict__ Wdec,
                                             const float* __restrict__ benc,
                                             float* __restrict__ ws) {
  __shared__ float sh[DECn];
  const int b = blockIdx.x;
  const int a = threadIdx.x;
  sh[a] = h[b * DECn + a];
  __syncthreads();
  float acc = 0.f;
  for (int d = 0; d < DECn; ++d) acc = fmaf(sh[d], Wdec[d * ATTNn + a], acc);
  ws[OFF_DB + b * ATTNn + a] = benc[a] + acc;
}

// ---------------------------------------------------------------------------
// k_main: fused f16-MFMA GEMM (enc @ W_enc) + DB + conv-expansion + tanh
//         + w_score dot -> score (atomic across the 4 column blocks)
// 128x128 tile, BK=32, double-buffered LDS, reg-staged (f32->f16 cvt in-flight),
// one barrier per K-step; loads for t+1 issued before compute of t.
// Grid: 1-D 2000 blocks, XCD-chunked bijective swizzle (2000 = 8*250), column
// block fastest within a chunk -> each A row panel fetched once per XCD/L2.
// ---------------------------------------------------------------------------
#define BM 128
#define BN 128
#define BK 32
#define LDKh 40   // f16 elems/row: 80 B row stride -> frag reads 2-way (free),
                  // staging writes hit the 1 KB/8-cycle bank floor exactly
#define NT (ENC2n / BK)   // 32

__global__ __launch_bounds__(256) void k_main(
    const float* __restrict__ A,        // [64000][1024] f32
    const _Float16* __restrict__ Wt,    // [512][1024] f16
    const float* __restrict__ Wc2s,     // [10][512]
    const float* __restrict__ wscore,   // [512]
    float* __restrict__ ws) {
  __shared__ _Float16 Asl[2][BM][LDKh];   // 20 KB
  __shared__ _Float16 Wsl[2][BN][LDKh];   // 20 KB
  const int tid = threadIdx.x;
  const int lane = tid & 63;
  const int wv = tid >> 6;
  const int wm = wv >> 1, wn = wv & 1;

  // XCD-chunked swizzle: consecutive dispatch ids round-robin XCDs; give each
  // XCD a contiguous chunk of 250 logical blocks, col-block fastest inside.
  const int l = blockIdx.x;
  const int lp = (l & 7) * 250 + (l >> 3);
  const int row0 = (lp >> 2) * BM;
  const int c0 = (lp & 3) * BN;

  // staging map: thread -> row sr = tid>>1, k-offset sk = (tid&1)*16
  const int sr = tid >> 1, sk = (tid & 1) * 16;
  const float* __restrict__ asrc = A + (size_t)(row0 + sr) * ENC2n + sk;
  const _Float16* __restrict__ wsrc = Wt + (size_t)(c0 + sr) * ENC2n + sk;

  const int lr = lane & 15, lg = lane >> 4;
  const int kk = lg * 8;

  f32x4 acc[4][4];
#pragma unroll
  for (int m = 0; m < 4; ++m)
#pragma unroll
    for (int n = 0; n < 4; ++n) acc[m][n] = (f32x4)0.f;

  // ---- prologue: stage tile 0 into buf 0 ----
  {
    const float4 a0 = *(const float4*)(asrc + 0);
    const float4 a1 = *(const float4*)(asrc + 4);
    const float4 a2 = *(const float4*)(asrc + 8);
    const float4 a3 = *(const float4*)(asrc + 12);
    const v8h w0 = *(const v8h*)(wsrc + 0);
    const v8h w1 = *(const v8h*)(wsrc + 8);
    v8h h0, h1;
    h0[0]=(_Float16)a0.x; h0[1]=(_Float16)a0.y; h0[2]=(_Float16)a0.z; h0[3]=(_Float16)a0.w;
    h0[4]=(_Float16)a1.x; h0[5]=(_Float16)a1.y; h0[6]=(_Float16)a1.z; h0[7]=(_Float16)a1.w;
    h1[0]=(_Float16)a2.x; h1[1]=(_Float16)a2.y; h1[2]=(_Float16)a2.z; h1[3]=(_Float16)a2.w;
    h1[4]=(_Float16)a3.x; h1[5]=(_Float16)a3.y; h1[6]=(_Float16)a3.z; h1[7]=(_Float16)a3.w;
    *(v8h*)&Asl[0][sr][sk]     = h0;
    *(v8h*)&Asl[0][sr][sk + 8] = h1;
    *(v8h*)&Wsl[0][sr][sk]     = w0;
    *(v8h*)&Wsl[0][sr][sk + 8] = w1;
  }
  __syncthreads();

  int cur = 0;
#pragma unroll 2
  for (int t = 0; t < NT - 1; ++t) {
    const int kn = (t + 1) * BK;
    // issue next-tile global loads (latency hides under this tile's compute)
    const float4 a0 = *(const float4*)(asrc + kn);
    const float4 a1 = *(const float4*)(asrc + kn + 4);
    const float4 a2 = *(const float4*)(asrc + kn + 8);
    const float4 a3 = *(const float4*)(asrc + kn + 12);
    const v8h w0 = *(const v8h*)(wsrc + kn);
    const v8h w1 = *(const v8h*)(wsrc + kn + 8);

    // compute tile t from buf[cur]
    v8h af[4], bf[4];
#pragma unroll
    for (int m = 0; m < 4; ++m) af[m] = *(const v8h*)&Asl[cur][wm * 64 + m * 16 + lr][kk];
#pragma unroll
    for (int n = 0; n < 4; ++n) bf[n] = *(const v8h*)&Wsl[cur][wn * 64 + n * 16 + lr][kk];
#pragma unroll
    for (int m = 0; m < 4; ++m)
#pragma unroll
      for (int n = 0; n < 4; ++n)
        acc[m][n] = __builtin_amdgcn_mfma_f32_16x16x32_f16(af[m], bf[n], acc[m][n], 0, 0, 0);

    // stage tile t+1 into buf[cur^1]
    v8h h0, h1;
    h0[0]=(_Float16)a0.x; h0[1]=(_Float16)a0.y; h0[2]=(_Float16)a0.z; h0[3]=(_Float16)a0.w;
    h0[4]=(_Float16)a1.x; h0[5]=(_Float16)a1.y; h0[6]=(_Float16)a1.z; h0[7]=(_Float16)a1.w;
    h1[0]=(_Float16)a2.x; h1[1]=(_Float16)a2.y; h1[2]=(_Float16)a2.z; h1[3]=(_Float16)a2.w;
    h1[4]=(_Float16)a3.x; h1[5]=(_Float16)a3.y; h1[6]=(_Float16)a3.z; h1[7]=(_Float16)a3.w;
    *(v8h*)&Asl[cur ^ 1][sr][sk]     = h0;
    *(v8h*)&Asl[cur ^ 1][sr][sk + 8] = h1;
    *(v8h*)&Wsl[cur ^ 1][sr][sk]     = w0;
    *(v8h*)&Wsl[cur ^ 1][sr][sk + 8] = w1;

    __syncthreads();
    cur ^= 1;
  }
  // final tile (compute only)
  {
    v8h af[4], bf[4];
#pragma unroll
    for (int m = 0; m < 4; ++m) af[m] = *(const v8h*)&Asl[cur][wm * 64 + m * 16 + lr][kk];
#pragma unroll
    for (int n = 0; n < 4; ++n) bf[n] = *(const v8h*)&Wsl[cur][wn * 64 + n * 16 + lr][kk];
#pragma unroll
    for (int m = 0; m < 4; ++m)
#pragma unroll
      for (int n = 0; n < 4; ++n)
        acc[m][n] = __builtin_amdgcn_mfma_f32_16x16x32_f16(af[m], bf[n], acc[m][n], 0, 0, 0);
  }

  // ---- epilogue ----
  __syncthreads();
  float* tcs = (float*)&Asl[0][0][0];     // reuse LDS: tmpconv slice [128][10]
  {
    const float* __restrict__ tsrc = ws + (size_t)row0 * NKn;
    for (int i = tid; i < BM * NKn; i += 256) tcs[i] = tsrc[i];
  }
  __syncthreads();

  const float* __restrict__ DB = ws + OFF_DB;
  float wc2[4][NKn], wsc[4];
  int cl[4];
#pragma unroll
  for (int fn = 0; fn < 4; ++fn) {
    cl[fn] = c0 + wn * 64 + fn * 16 + lr;
    wsc[fn] = wscore[cl[fn]];
#pragma unroll
    for (int k = 0; k < NKn; ++k) wc2[fn][k] = Wc2s[k * ATTNn + cl[fn]];
  }

#pragma unroll
  for (int fm = 0; fm < 4; ++fm) {
#pragma unroll
    for (int r = 0; r < 4; ++r) {
      const int rowL = wm * 64 + fm * 16 + lg * 4 + r;
      const int grow = row0 + rowL;
      const int b = grow / Tn;
      const float* __restrict__ tk = &tcs[rowL * NKn];
      float tkv[NKn];
#pragma unroll
      for (int k = 0; k < NKn; ++k) tkv[k] = tk[k];
      float p = 0.f;
#pragma unroll
      for (int fn = 0; fn < 4; ++fn) {
        float v = acc[fm][fn][r] + DB[b * ATTNn + cl[fn]];
#pragma unroll
        for (int k = 0; k < NKn; ++k) v = fmaf(tkv[k], wc2[fn][k], v);
        p = fmaf(wsc[fn], fast_tanh(v), p);
      }
      p += __shfl_down(p, 8, 16);
      p += __shfl_down(p, 4, 16);
      p += __shfl_down(p, 2, 16);
      p += __shfl_down(p, 1, 16);
      if (lr == 0) atomicAdd(&ws[OFF_SCORE + grow], p);
    }
  }
}

// ---------------------------------------------------------------------------
// k_softmax: masked softmax over T per batch row
// ---------------------------------------------------------------------------
__global__ __launch_bounds__(256) void k_softmax(const float* __restrict__ ws,
                                                 const float* __restrict__ mask,
                                                 float* __restrict__ out) {
  const int b = blockIdx.x, tid = threadIdx.x;
  const float* __restrict__ s = ws + OFF_SCORE + b * Tn;
  const float* __restrict__ mrow = mask + b * Tn;
  float* __restrict__ orow = out + b * Tn;
  __shared__ float red[4];

  float m = -1e30f;
  for (int t = tid; t < Tn; t += 256) m = fmaxf(m, s[t]);
#pragma unroll
  for (int off = 32; off; off >>= 1) m = fmaxf(m, __shfl_down(m, off));
  if ((tid & 63) == 0) red[tid >> 6] = m;
  __syncthreads();
  m = fmaxf(fmaxf(red[0], red[1]), fmaxf(red[2], red[3]));
  __syncthreads();

  float sum = 0.f;
  for (int t = tid; t < Tn; t += 256) {
    const float e = expf(s[t] - m) * mrow[t];
    orow[t] = e;
    sum += e;
  }
#pragma unroll
  for (int off = 32; off; off >>= 1) sum += __shfl_down(sum, off);
  if ((tid & 63) == 0) red[tid >> 6] = sum;
  __syncthreads();
  sum = red[0] + red[1] + red[2] + red[3];
  const float inv = 1.f / sum;
  for (int t = tid; t < Tn; t += 256) orow[t] *= inv;
}

// ---------------------------------------------------------------------------
extern "C" void kernel_launch(void* const* d_in, const int* in_sizes, int n_in,
                              void* d_out, int out_size, void* d_ws, size_t ws_size,
                              hipStream_t stream) {
  const float* enc   = (const float*)d_in[0];
  const float* hid   = (const float*)d_in[1];
  const float* alpha = (const float*)d_in[2];
  const float* mask  = (const float*)d_in[3];
  const float* Wconv = (const float*)d_in[4];
  const float* Wc2s  = (const float*)d_in[5];
  const float* Wenc  = (const float*)d_in[6];
  const float* benc  = (const float*)d_in[7];
  const float* Wdec  = (const float*)d_in[8];
  const float* wscr  = (const float*)d_in[9];
  float* out = (float*)d_out;
  float* ws  = (float*)d_ws;
  _Float16* Wt = (_Float16*)(ws + OFF_WT);

  k_wt<<<dim3(ENC2n / 32, ATTNn / 32), 256, 0, stream>>>(Wenc, Wt);
  k_conv<<<dim3((Tn + 255) / 256, Bn), 256, 0, stream>>>(alpha, Wconv, ws);
  k_dec<<<Bn, DECn, 0, stream>>>(hid, Wdec, benc, ws);
  k_main<<<2000, 256, 0, stream>>>(enc, Wt, Wc2s, wscr, ws);
  k_softmax<<<Bn, 256, 0, stream>>>(ws, mask, out);
}